// Round 19
// baseline (723.345 us; speedup 1.0000x reference)
//
#include <hip/hip_runtime.h>
#include <hip/hip_bf16.h>

// MoE: T=16384 tokens, H=1024, I=2048, E=8, K=2 (top-2, renormalized)
#define T_TOK 16384
#define H_DIM 1024
#define I_DIM 2048
#define E_NUM 8

typedef short short8 __attribute__((ext_vector_type(8)));
typedef float f32x4 __attribute__((ext_vector_type(4)));

__device__ __forceinline__ unsigned short f2bf(float f) {
  union { float f; unsigned u; } v; v.f = f;
  unsigned r = (v.u + 0x7FFFu + ((v.u >> 16) & 1u)) >> 16;
  return (unsigned short)r;
}
__device__ __forceinline__ float bf2f(unsigned short u) {
  union { unsigned u; float f; } v; v.u = ((unsigned)u) << 16;
  return v.f;
}

__device__ __forceinline__ void gload16(const void* g, void* l) {
  __builtin_amdgcn_global_load_lds(
      (const __attribute__((address_space(1))) unsigned int*)g,
      (__attribute__((address_space(3))) unsigned int*)l, 16, 0, 0);
}

#define VMCNT4() asm volatile("s_waitcnt vmcnt(4)" ::: "memory")
#define VMCNT2() asm volatile("s_waitcnt vmcnt(2)" ::: "memory")
#define VMCNT0() asm volatile("s_waitcnt vmcnt(0)" ::: "memory")
#define LGKM0()  asm volatile("s_waitcnt lgkmcnt(0)" ::: "memory")
#define BAR() __builtin_amdgcn_s_barrier()
#define SCHEDFENCE() __builtin_amdgcn_sched_barrier(0)
#define PRIO1() __builtin_amdgcn_s_setprio(1)
#define PRIO0() __builtin_amdgcn_s_setprio(0)

// ---- Phase 1: fused convert x (fp32->bf16) + router logits/top-2 ----
__global__ __launch_bounds__(256) void convert_router_kernel(
    const float* __restrict__ x, const float* __restrict__ gw,
    unsigned short* __restrict__ xb,
    int* __restrict__ tke, float* __restrict__ pwv) {
  const int tid = threadIdx.x;
  const int lane = tid & 63;
  const int wv = tid >> 6;
  const int t = blockIdx.x * 4 + wv;
  const float* xr = x + (size_t)t * H_DIM;
  unsigned short* xbr = xb + (size_t)t * H_DIM;

  float acc[8] = {0.f, 0.f, 0.f, 0.f, 0.f, 0.f, 0.f, 0.f};
#pragma unroll
  for (int i = 0; i < 16; ++i) {
    const int h = i * 64 + lane;
    float xv = xr[h];
    xbr[h] = f2bf(xv);
    const float4 g0 = *(const float4*)(gw + (size_t)h * 8);
    const float4 g1 = *(const float4*)(gw + (size_t)h * 8 + 4);
    acc[0] += xv * g0.x; acc[1] += xv * g0.y;
    acc[2] += xv * g0.z; acc[3] += xv * g0.w;
    acc[4] += xv * g1.x; acc[5] += xv * g1.y;
    acc[6] += xv * g1.z; acc[7] += xv * g1.w;
  }
#pragma unroll
  for (int e = 0; e < 8; ++e) {
#pragma unroll
    for (int off = 32; off; off >>= 1) acc[e] += __shfl_xor(acc[e], off);
  }
  int e1 = 0; float l1 = acc[0];
#pragma unroll
  for (int e = 1; e < 8; ++e) if (acc[e] > l1) { l1 = acc[e]; e1 = e; }
  int first_non = (e1 == 0) ? 1 : 0;
  int e2 = first_non; float l2 = acc[first_non];
#pragma unroll
  for (int e = 0; e < 8; ++e) {
    if (e == e1 || e == first_non) continue;
    if (acc[e] > l2) { l2 = acc[e]; e2 = e; }
  }
  float r = expf(l2 - l1);
  float w1 = 1.f / (1.f + r);
  float w2 = r / (1.f + r);
  if (lane == 0) {
    pwv[2 * t] = w1;
    pwv[2 * t + 1] = w2;
    tke[t] = e1 | (e2 << 4);
  }
}

// ---- Phase 2: build per-expert lists, wave-aggregated atomics ----
__global__ __launch_bounds__(256) void build_lists_kernel(
    const int* __restrict__ tke, int* __restrict__ list, int* __restrict__ cnt) {
  const int t = blockIdx.x * 256 + threadIdx.x;
  const int lane = threadIdx.x & 63;
  const int pk = tke[t];
  const int ee[2] = {pk & 15, (pk >> 4) & 15};
#pragma unroll
  for (int phase = 0; phase < 2; ++phase) {
    const int e = ee[phase];
    const int pid = 2 * t + phase;
#pragma unroll
    for (int ex = 0; ex < E_NUM; ++ex) {
      unsigned long long mask = __ballot(e == ex);
      if (e == ex) {
        unsigned long long below = mask & ((1ull << lane) - 1ull);
        int rank = __popcll(below);
        int leader = __ffsll((unsigned long long)mask) - 1;
        int base = 0;
        if (lane == leader) base = atomicAdd(&cnt[ex], __popcll(mask));
        base = __shfl(base, leader);
        list[ex * T_TOK + base + rank] = pid;
      }
    }
  }
}

// ------- transpose+convert: src[e][K][N] fp32 -> dst[e][N][K] bf16 ----------
__global__ __launch_bounds__(256) void transpose_convert(
    const float* __restrict__ src, unsigned short* __restrict__ dst, int K, int N) {
  __shared__ float t[128][65];
  const int e = blockIdx.x, kt = blockIdx.y, nt = blockIdx.z;
  const float* s = src + (size_t)e * K * N + (size_t)(kt * 128) * N + nt * 64;
  unsigned short* d = dst + (size_t)e * N * K + (size_t)(nt * 64) * K + kt * 128;
  const int tid = threadIdx.x;
  const int lr = tid & 15, row = tid >> 4;
#pragma unroll
  for (int p = 0; p < 8; ++p) {
    int k = row + p * 16;
    float4 v = *(const float4*)(s + (size_t)k * N + lr * 4);
    t[k][lr * 4 + 0] = v.x;
    t[k][lr * 4 + 1] = v.y;
    t[k][lr * 4 + 2] = v.z;
    t[k][lr * 4 + 3] = v.w;
  }
  __syncthreads();
  const int kc = tid & 15, nr = tid >> 4;
#pragma unroll
  for (int p = 0; p < 4; ++p) {
    int n = nr + p * 16;
    short8 o;
#pragma unroll
    for (int j = 0; j < 8; ++j) o[j] = (short)f2bf(t[kc * 8 + j][n]);
    *(short8*)&d[(size_t)n * K + kc * 8] = o;
  }
}

// ------- GEMM A: h = w * silu(x@Wg) * (x@Wu), grouped by expert -------------
// [R18 proven] 128x64 tile, BK=32, depth-2 dbuf, single barrier/K-step,
// plain n-major grid. grid (I/64, E*128).
__global__ __launch_bounds__(256, 3) void gemm_gateup(
    const unsigned short* __restrict__ xb, const unsigned short* __restrict__ wgt,
    const unsigned short* __restrict__ wut, const int* __restrict__ list,
    const int* __restrict__ cnt, const float* __restrict__ pwv,
    unsigned short* __restrict__ hbuf) {
  __shared__ unsigned short As[2][128 * 32];
  __shared__ unsigned short Bg[2][64 * 32];
  __shared__ unsigned short Bu[2][64 * 32];
  __shared__ int rows_s[128];
  __shared__ float pws[128];

  const int tid = threadIdx.x;
  const int e = blockIdx.y >> 7;
  const int mt = blockIdx.y & 127;
  const int ce = cnt[e];
  if (mt * 128 >= ce) return;
  const int n0 = blockIdx.x * 64;

  if (tid < 128) {
    int idx = mt * 128 + tid;
    int pid = list[e * T_TOK + (idx < ce ? idx : 0)];
    rows_s[tid] = pid;
    pws[tid] = pwv[pid];
  }
  __syncthreads();

  const int s0 = tid, s1 = 256 + tid;
  const int q0 = (((s0 & 3) ^ ((s0 >> 3) & 3)) * 8);
  const int q1 = (((s1 & 3) ^ ((s1 >> 3) & 3)) * 8);
  const int tok0 = rows_s[s0 >> 2] >> 1, tok1 = rows_s[s1 >> 2] >> 1;

  const unsigned short* wg_base = wgt + ((size_t)e * I_DIM + n0) * H_DIM;
  const unsigned short* wu_base = wut + ((size_t)e * I_DIM + n0) * H_DIM;
  const unsigned short* a_src0 = xb + (size_t)tok0 * H_DIM + q0;
  const unsigned short* a_src1 = xb + (size_t)tok1 * H_DIM + q1;
  const unsigned short* g_src0 = wg_base + (size_t)(s0 >> 2) * H_DIM + q0;
  const unsigned short* u_src0 = wu_base + (size_t)(s0 >> 2) * H_DIM + q0;

#define STAGE_GU(b, k0)                         \
  do {                                          \
    gload16(a_src0 + (k0), &As[b][s0 * 8]);     \
    gload16(a_src1 + (k0), &As[b][s1 * 8]);     \
    gload16(g_src0 + (k0), &Bg[b][s0 * 8]);     \
    gload16(u_src0 + (k0), &Bu[b][s0 * 8]);     \
  } while (0)

  f32x4 zero = {0.f, 0.f, 0.f, 0.f};
  f32x4 accg[4][2], accu[4][2];
#pragma unroll
  for (int m = 0; m < 4; ++m)
#pragma unroll
    for (int n = 0; n < 2; ++n) { accg[m][n] = zero; accu[m][n] = zero; }

  const int lane = tid & 63;
  const int wv = tid >> 6;
  const int wr = (wv >> 1) * 64;
  const int wc = (wv & 1) * 32;
  const int lr = lane & 15;
  const int lks = (((lane >> 4) ^ ((lr >> 1) & 3)) * 8);

  STAGE_GU(0, 0);

  for (int kt = 0; kt < H_DIM / 32; ++kt) {
    const int cur = kt & 1;
    VMCNT0();
    BAR();
    SCHEDFENCE();
    if (kt < H_DIM / 32 - 1) STAGE_GU(cur ^ 1, (kt + 1) * 32);
    const unsigned short* Ab = As[cur];
    const unsigned short* Bgb = Bg[cur];
    const unsigned short* Bub = Bu[cur];
    short8 a[4], bg[2], bu[2];
#pragma unroll
    for (int m = 0; m < 4; ++m)
      a[m] = *(const short8*)&Ab[(wr + m * 16 + lr) * 32 + lks];
#pragma unroll
    for (int n = 0; n < 2; ++n) {
      bg[n] = *(const short8*)&Bgb[(wc + n * 16 + lr) * 32 + lks];
      bu[n] = *(const short8*)&Bub[(wc + n * 16 + lr) * 32 + lks];
    }
    PRIO1();
#pragma unroll
    for (int m = 0; m < 4; ++m)
#pragma unroll
      for (int n = 0; n < 2; ++n) {
        accg[m][n] = __builtin_amdgcn_mfma_f32_16x16x32_bf16(a[m], bg[n], accg[m][n], 0, 0, 0);
        accu[m][n] = __builtin_amdgcn_mfma_f32_16x16x32_bf16(a[m], bu[n], accu[m][n], 0, 0, 0);
      }
    PRIO0();
  }
#undef STAGE_GU

  const int rr = (lane >> 4) * 4;
#pragma unroll
  for (int m = 0; m < 4; ++m) {
#pragma unroll
    for (int j = 0; j < 4; ++j) {
      int tr = wr + m * 16 + rr + j;
      if (mt * 128 + tr < ce) {
        int pid = rows_s[tr];
        float wgt_r = pws[tr];
        size_t rowb = (size_t)pid * I_DIM + n0 + wc;
#pragma unroll
        for (int n = 0; n < 2; ++n) {
          float g = accg[m][n][j];
          float u = accu[m][n][j];
          float hv = wgt_r * (g / (1.f + __expf(-g))) * u;
          hbuf[rowb + n * 16 + lr] = f2bf(hv);
        }
      }
    }
  }
}

// ------- GEMM B v2 (8-phase, COUNTED vmcnt): pbuf[pid] = h[pid] @ Wd --------
// BM=BN=256, BK=64, 512 thr (8 waves 2Mx4N, per-wave 128x64), LDS 128KB.
// Staging split 2-loads/phase; tile-boundary wait = vmcnt(2) (2 loads stay in
// flight across the barrier -- the T4 lever R13 got wrong); per-phase double
// barriers around each 16-MFMA cluster. grid (H/256, E*64), chunked XCD remap.
__global__ __launch_bounds__(512, 2) void gemm_down8(
    const unsigned short* __restrict__ hbuf, const unsigned short* __restrict__ wdt,
    const int* __restrict__ list, const int* __restrict__ cnt,
    unsigned short* __restrict__ pbuf) {
  __shared__ unsigned short As[2][256 * 64];  // 64 KB
  __shared__ unsigned short Bs[2][256 * 64];  // 64 KB
  __shared__ int rows_s[256];

  const int tid = threadIdx.x;
  // chunked XCD remap over 2048 blocks
  const int flat = blockIdx.x + 4 * blockIdx.y;
  const int sw = (flat & 7) * (2048 / 8) + (flat >> 3);
  const int ntile = sw & 3;           // 4 n-tiles
  const int mb = sw >> 2;             // 512 m-blocks
  const int e = mb >> 6;
  const int mt = mb & 63;
  const int ce = cnt[e];
  if (mt * 256 >= ce) return;
  const int n0 = ntile * 256;

  if (tid < 256) {
    int idx = mt * 256 + tid;
    rows_s[tid] = list[e * T_TOK + (idx < ce ? idx : 0)];
  }
  __syncthreads();

  // staging: 4 slots/thread per matrix; slot s = j*512+tid, row = s>>3,
  // phys chunk s&7 holds logical (s&7)^(row&7) [source pre-swizzled]
  const unsigned short* wd_base = wdt + ((size_t)e * H_DIM + n0) * I_DIM;
  const unsigned short* a_base[4];
  const unsigned short* b_base[4];
#pragma unroll
  for (int j = 0; j < 4; ++j) {
    int slot = j * 512 + tid;
    int row = slot >> 3;
    int cs = ((slot & 7) ^ (row & 7)) * 8;
    a_base[j] = hbuf + (size_t)rows_s[row] * I_DIM + cs;
    b_base[j] = wd_base + (size_t)row * I_DIM + cs;
  }

#define LD_A(b, t, j0, j1)                                     \
  do {                                                         \
    gload16(a_base[j0] + (t) * 64, &As[b][(j0 * 512 + tid) * 8]); \
    gload16(a_base[j1] + (t) * 64, &As[b][(j1 * 512 + tid) * 8]); \
  } while (0)
#define LD_B(b, t, j0, j1)                                     \
  do {                                                         \
    gload16(b_base[j0] + (t) * 64, &Bs[b][(j0 * 512 + tid) * 8]); \
    gload16(b_base[j1] + (t) * 64, &Bs[b][(j1 * 512 + tid) * 8]); \
  } while (0)

  f32x4 zero = {0.f, 0.f, 0.f, 0.f};
  f32x4 acc[8][4];
#pragma unroll
  for (int m = 0; m < 8; ++m)
#pragma unroll
    for (int n = 0; n < 4; ++n) acc[m][n] = zero;

  const int lane = tid & 63;
  const int wv = tid >> 6;
  const int wm = wv >> 2;          // 0,1 -> row offset wm*128
  const int wn = wv & 3;           // 0..3 -> col offset wn*64
  const int lr = lane & 15;
  const int lg = lane >> 4;        // 0..3
  const int pc0 = ((lg) ^ (lr & 7)) * 8;       // k-half 0, swizzled
  const int pc1 = ((lg + 4) ^ (lr & 7)) * 8;   // k-half 1, swizzled

  short8 a[4][2], b[4][2];

  // prologue: full tile 0
  LD_A(0, 0, 0, 1); LD_A(0, 0, 2, 3);
  LD_B(0, 0, 0, 1); LD_B(0, 0, 2, 3);

  const int NT = I_DIM / 64;  // 32
  for (int t = 0; t < NT; ++t) {
    const int cur = t & 1;
    const int nxt = cur ^ 1;
    const bool more = (t + 1 < NT);
    // issue first 2 loads of tile t+1, THEN counted wait: tile t landed,
    // these 2 stay in flight across the barrier (never drain to 0 mid-loop).
    if (more) { LD_A(nxt, t + 1, 0, 1); VMCNT2(); } else { VMCNT0(); }
    BAR();
    SCHEDFENCE();

    const unsigned short* Ab = As[cur];
    const unsigned short* Bb = Bs[cur];

    // ---- phase 1: q(0,0) -- read a[0..3], b[0..1]; stage; 16 MFMA ----
#pragma unroll
    for (int m = 0; m < 4; ++m) {
      int row = (wm * 128 + m * 16 + lr) * 64;
      a[m][0] = *(const short8*)&Ab[row + pc0];
      a[m][1] = *(const short8*)&Ab[row + pc1];
    }
#pragma unroll
    for (int n = 0; n < 2; ++n) {
      int row = (wn * 64 + n * 16 + lr) * 64;
      b[n][0] = *(const short8*)&Bb[row + pc0];
      b[n][1] = *(const short8*)&Bb[row + pc1];
    }
    if (more) LD_A(nxt, t + 1, 2, 3);
    BAR(); LGKM0();
    SCHEDFENCE();
    PRIO1();
#pragma unroll
    for (int m = 0; m < 4; ++m)
#pragma unroll
      for (int n = 0; n < 2; ++n) {
        acc[m][n] = __builtin_amdgcn_mfma_f32_16x16x32_bf16(a[m][0], b[n][0], acc[m][n], 0, 0, 0);
        acc[m][n] = __builtin_amdgcn_mfma_f32_16x16x32_bf16(a[m][1], b[n][1], acc[m][n], 0, 0, 0);
      }
    PRIO0();
    BAR();

    // ---- phase 2: q(0,1) -- read b[2..3]; stage; 16 MFMA ----
#pragma unroll
    for (int n = 2; n < 4; ++n) {
      int row = (wn * 64 + n * 16 + lr) * 64;
      b[n][0] = *(const short8*)&Bb[row + pc0];
      b[n][1] = *(const short8*)&Bb[row + pc1];
    }
    if (more) LD_B(nxt, t + 1, 0, 1);
    BAR(); LGKM0();
    SCHEDFENCE();
    PRIO1();
#pragma unroll
    for (int m = 0; m < 4; ++m)
#pragma unroll
      for (int n = 2; n < 4; ++n) {
        acc[m][n] = __builtin_amdgcn_mfma_f32_16x16x32_bf16(a[m][0], b[n][0], acc[m][n], 0, 0, 0);
        acc[m][n] = __builtin_amdgcn_mfma_f32_16x16x32_bf16(a[m][1], b[n][1], acc[m][n], 0, 0, 0);
      }
    PRIO0();
    BAR();

    // ---- phase 3: q(1,0) -- read a[4..7] (reuse regs); stage; 16 MFMA ----
#pragma unroll
    for (int m = 0; m < 4; ++m) {
      int row = (wm * 128 + (m + 4) * 16 + lr) * 64;
      a[m][0] = *(const short8*)&Ab[row + pc0];
      a[m][1] = *(const short8*)&Ab[row + pc1];
    }
    if (more) LD_B(nxt, t + 1, 2, 3);
    BAR(); LGKM0();
    SCHEDFENCE();
    PRIO1();
#pragma unroll
    for (int m = 0; m < 4; ++m)
#pragma unroll
      for (int n = 0; n < 2; ++n) {
        acc[m + 4][n] = __builtin_amdgcn_mfma_f32_16x16x32_bf16(a[m][0], b[n][0], acc[m + 4][n], 0, 0, 0);
        acc[m + 4][n] = __builtin_amdgcn_mfma_f32_16x16x32_bf16(a[m][1], b[n][1], acc[m + 4][n], 0, 0, 0);
      }
    PRIO0();
    BAR();

    // ---- phase 4: q(1,1) -- no reads; 16 MFMA ----
    PRIO1();
#pragma unroll
    for (int m = 0; m < 4; ++m)
#pragma unroll
      for (int n = 2; n < 4; ++n) {
        acc[m + 4][n] = __builtin_amdgcn_mfma_f32_16x16x32_bf16(a[m][0], b[n][0], acc[m + 4][n], 0, 0, 0);
        acc[m + 4][n] = __builtin_amdgcn_mfma_f32_16x16x32_bf16(a[m][1], b[n][1], acc[m + 4][n], 0, 0, 0);
      }
    PRIO0();
    BAR();  // end of tile: all waves done reading buf cur
  }
#undef LD_A
#undef LD_B

  const int rr = lg * 4;
#pragma unroll
  for (int m = 0; m < 8; ++m) {
#pragma unroll
    for (int j = 0; j < 4; ++j) {
      int tr = wm * 128 + m * 16 + rr + j;
      if (mt * 256 + tr < ce) {
        int pid = rows_s[tr];
        unsigned short* orow = pbuf + (size_t)pid * H_DIM + n0 + wn * 64;
#pragma unroll
        for (int n = 0; n < 4; ++n)
          orow[n * 16 + lr] = f2bf(acc[m][n][j]);
      }
    }
  }
}

// ---- combine: out[t] = pair[2t] + pair[2t+1], in-place bf16->fp32 ----------
__global__ __launch_bounds__(256) void combine_kernel(float* __restrict__ out) {
  const int tid = threadIdx.x, lane = tid & 63, wv = tid >> 6;
  const int t = blockIdx.x * 4 + wv;
  const unsigned short* p = (const unsigned short*)out;
  const unsigned short* r0 = p + (size_t)(2 * t) * H_DIM + lane * 16;
  const unsigned short* r1 = p + (size_t)(2 * t + 1) * H_DIM + lane * 16;
  short8 a0 = *(const short8*)r0;
  short8 a1 = *(const short8*)(r0 + 8);
  short8 b0 = *(const short8*)r1;
  short8 b1 = *(const short8*)(r1 + 8);
  float res[16];
#pragma unroll
  for (int j = 0; j < 8; ++j) {
    res[j] = bf2f((unsigned short)a0[j]) + bf2f((unsigned short)b0[j]);
    res[8 + j] = bf2f((unsigned short)a1[j]) + bf2f((unsigned short)b1[j]);
  }
  float* orow = out + (size_t)t * H_DIM + lane * 16;
#pragma unroll
  for (int j = 0; j < 4; ++j) {
    float4 w = {res[4 * j], res[4 * j + 1], res[4 * j + 2], res[4 * j + 3]};
    ((float4*)orow)[j] = w;
  }
}

// ---------------- launch ----------------
extern "C" void kernel_launch(void* const* d_in, const int* in_sizes, int n_in,
                              void* d_out, int out_size, void* d_ws, size_t ws_size,
                              hipStream_t stream) {
  const float* x = (const float*)d_in[0];
  const float* gw = (const float*)d_in[1];
  const float* wgf = (const float*)d_in[2];
  const float* wuf = (const float*)d_in[3];
  const float* wdf = (const float*)d_in[4];

  const size_t off_xb   = 0;
  const size_t off_wdt  = 33554432;
  const size_t off_h    = 67108864;
  const size_t off_list = 201326592;
  const size_t off_pw   = 201850880;
  const size_t off_cnt  = 201981952;
  const size_t ws_needed = off_cnt + 64;
  if (ws_size < ws_needed) return;

  char* ws = (char*)d_ws;
  unsigned short* xb   = (unsigned short*)(ws + off_xb);
  unsigned short* wdt  = (unsigned short*)(ws + off_wdt);
  unsigned short* hbuf = (unsigned short*)(ws + off_h);
  int*   list = (int*)(ws + off_list);
  float* pwv  = (float*)(ws + off_pw);
  int*   cnt  = (int*)(ws + off_cnt);
  int*   tke  = (int*)(ws + off_h);  // parks in hbuf (unused until gemm_gateup)

  unsigned short* wgt = (unsigned short*)d_out;
  unsigned short* wut = (unsigned short*)d_out + (size_t)E_NUM * H_DIM * I_DIM;
  unsigned short* pbuf = (unsigned short*)d_out;

  hipMemsetAsync(cnt, 0, E_NUM * sizeof(int), stream);

  convert_router_kernel<<<T_TOK / 4, 256, 0, stream>>>(x, gw, xb, tke, pwv);
  build_lists_kernel<<<T_TOK / 256, 256, 0, stream>>>(tke, list, cnt);
  transpose_convert<<<dim3(E_NUM, H_DIM / 128, I_DIM / 64), 256, 0, stream>>>(
      wgf, wgt, H_DIM, I_DIM);
  transpose_convert<<<dim3(E_NUM, H_DIM / 128, I_DIM / 64), 256, 0, stream>>>(
      wuf, wut, H_DIM, I_DIM);
  transpose_convert<<<dim3(E_NUM, I_DIM / 128, H_DIM / 64), 256, 0, stream>>>(
      wdf, wdt, I_DIM, H_DIM);

  gemm_gateup<<<dim3(I_DIM / 64, E_NUM * 128), 256, 0, stream>>>(
      xb, wgt, wut, list, cnt, pwv, hbuf);

  gemm_down8<<<dim3(H_DIM / 256, E_NUM * 64), 512, 0, stream>>>(
      hbuf, wdt, list, cnt, pbuf);

  combine_kernel<<<T_TOK / 4, 256, 0, stream>>>((float*)d_out);
}

// Round 20
// 667.694 us; speedup vs baseline: 1.0833x; 1.0833x over previous
//
#include <hip/hip_runtime.h>
#include <hip/hip_bf16.h>

// MoE: T=16384 tokens, H=1024, I=2048, E=8, K=2 (top-2, renormalized)
#define T_TOK 16384
#define H_DIM 1024
#define I_DIM 2048
#define E_NUM 8

typedef short short8 __attribute__((ext_vector_type(8)));
typedef float f32x4 __attribute__((ext_vector_type(4)));

__device__ __forceinline__ unsigned short f2bf(float f) {
  union { float f; unsigned u; } v; v.f = f;
  unsigned r = (v.u + 0x7FFFu + ((v.u >> 16) & 1u)) >> 16;
  return (unsigned short)r;
}
__device__ __forceinline__ float bf2f(unsigned short u) {
  union { unsigned u; float f; } v; v.u = ((unsigned)u) << 16;
  return v.f;
}

__device__ __forceinline__ void gload16(const void* g, void* l) {
  __builtin_amdgcn_global_load_lds(
      (const __attribute__((address_space(1))) unsigned int*)g,
      (__attribute__((address_space(3))) unsigned int*)l, 16, 0, 0);
}

#define VMCNT4() asm volatile("s_waitcnt vmcnt(4)" ::: "memory")
#define VMCNT0() asm volatile("s_waitcnt vmcnt(0)" ::: "memory")
#define BAR() __builtin_amdgcn_s_barrier()
#define SCHEDFENCE() __builtin_amdgcn_sched_barrier(0)
#define PRIO1() __builtin_amdgcn_s_setprio(1)
#define PRIO0() __builtin_amdgcn_s_setprio(0)

// ---- Phase 1: fused convert x (fp32->bf16) + router logits/top-2 ----
// grid T/8, block 256; each wave handles TWO tokens, sharing the gw row
// loads between them (halves gw issue per token). stride-1 lane mapping.
__global__ __launch_bounds__(256) void convert_router_kernel(
    const float* __restrict__ x, const float* __restrict__ gw,
    unsigned short* __restrict__ xb,
    int* __restrict__ tke, float* __restrict__ pwv) {
  const int tid = threadIdx.x;
  const int lane = tid & 63;
  const int wv = tid >> 6;
  const int t0 = blockIdx.x * 8 + wv * 2;
  const int t1 = t0 + 1;
  const float* xr0 = x + (size_t)t0 * H_DIM;
  const float* xr1 = x + (size_t)t1 * H_DIM;
  unsigned short* xbr0 = xb + (size_t)t0 * H_DIM;
  unsigned short* xbr1 = xb + (size_t)t1 * H_DIM;

  float aA[8] = {0.f, 0.f, 0.f, 0.f, 0.f, 0.f, 0.f, 0.f};
  float aB[8] = {0.f, 0.f, 0.f, 0.f, 0.f, 0.f, 0.f, 0.f};
#pragma unroll
  for (int i = 0; i < 16; ++i) {
    const int h = i * 64 + lane;
    float xv0 = xr0[h];
    float xv1 = xr1[h];
    xbr0[h] = f2bf(xv0);
    xbr1[h] = f2bf(xv1);
    const float4 g0 = *(const float4*)(gw + (size_t)h * 8);
    const float4 g1 = *(const float4*)(gw + (size_t)h * 8 + 4);
    aA[0] += xv0 * g0.x; aA[1] += xv0 * g0.y;
    aA[2] += xv0 * g0.z; aA[3] += xv0 * g0.w;
    aA[4] += xv0 * g1.x; aA[5] += xv0 * g1.y;
    aA[6] += xv0 * g1.z; aA[7] += xv0 * g1.w;
    aB[0] += xv1 * g0.x; aB[1] += xv1 * g0.y;
    aB[2] += xv1 * g0.z; aB[3] += xv1 * g0.w;
    aB[4] += xv1 * g1.x; aB[5] += xv1 * g1.y;
    aB[6] += xv1 * g1.z; aB[7] += xv1 * g1.w;
  }
#pragma unroll
  for (int e = 0; e < 8; ++e) {
#pragma unroll
    for (int off = 32; off; off >>= 1) {
      aA[e] += __shfl_xor(aA[e], off);
      aB[e] += __shfl_xor(aB[e], off);
    }
  }
  if (lane == 0) {
#pragma unroll
    for (int s = 0; s < 2; ++s) {
      const float* acc = s ? aB : aA;
      const int t = s ? t1 : t0;
      int e1 = 0; float l1 = acc[0];
#pragma unroll
      for (int e = 1; e < 8; ++e) if (acc[e] > l1) { l1 = acc[e]; e1 = e; }
      int first_non = (e1 == 0) ? 1 : 0;
      int e2 = first_non; float l2 = acc[first_non];
#pragma unroll
      for (int e = 0; e < 8; ++e) {
        if (e == e1 || e == first_non) continue;
        if (acc[e] > l2) { l2 = acc[e]; e2 = e; }
      }
      float r = expf(l2 - l1);
      pwv[2 * t] = 1.f / (1.f + r);
      pwv[2 * t + 1] = r / (1.f + r);
      tke[t] = e1 | (e2 << 4);
    }
  }
}

// ---- Phase 2: build per-expert lists, wave-aggregated atomics ----
__global__ __launch_bounds__(256) void build_lists_kernel(
    const int* __restrict__ tke, int* __restrict__ list, int* __restrict__ cnt) {
  const int t = blockIdx.x * 256 + threadIdx.x;
  const int lane = threadIdx.x & 63;
  const int pk = tke[t];
  const int ee[2] = {pk & 15, (pk >> 4) & 15};
#pragma unroll
  for (int phase = 0; phase < 2; ++phase) {
    const int e = ee[phase];
    const int pid = 2 * t + phase;
#pragma unroll
    for (int ex = 0; ex < E_NUM; ++ex) {
      unsigned long long mask = __ballot(e == ex);
      if (e == ex) {
        unsigned long long below = mask & ((1ull << lane) - 1ull);
        int rank = __popcll(below);
        int leader = __ffsll((unsigned long long)mask) - 1;
        int base = 0;
        if (lane == leader) base = atomicAdd(&cnt[ex], __popcll(mask));
        base = __shfl(base, leader);
        list[ex * T_TOK + base + rank] = pid;
      }
    }
  }
}

// ------- transpose+convert: src[e][K][N] fp32 -> dst[e][N][K] bf16 ----------
__global__ __launch_bounds__(256) void transpose_convert(
    const float* __restrict__ src, unsigned short* __restrict__ dst, int K, int N) {
  __shared__ float t[128][65];
  const int e = blockIdx.x, kt = blockIdx.y, nt = blockIdx.z;
  const float* s = src + (size_t)e * K * N + (size_t)(kt * 128) * N + nt * 64;
  unsigned short* d = dst + (size_t)e * N * K + (size_t)(nt * 64) * K + kt * 128;
  const int tid = threadIdx.x;
  const int lr = tid & 15, row = tid >> 4;
#pragma unroll
  for (int p = 0; p < 8; ++p) {
    int k = row + p * 16;
    float4 v = *(const float4*)(s + (size_t)k * N + lr * 4);
    t[k][lr * 4 + 0] = v.x;
    t[k][lr * 4 + 1] = v.y;
    t[k][lr * 4 + 2] = v.z;
    t[k][lr * 4 + 3] = v.w;
  }
  __syncthreads();
  const int kc = tid & 15, nr = tid >> 4;
#pragma unroll
  for (int p = 0; p < 4; ++p) {
    int n = nr + p * 16;
    short8 o;
#pragma unroll
    for (int j = 0; j < 8; ++j) o[j] = (short)f2bf(t[kc * 8 + j][n]);
    *(short8*)&d[(size_t)n * K + kc * 8] = o;
  }
}

// ------- GEMM A: h = w * silu(x@Wg) * (x@Wu), grouped by expert -------------
// [R18 proven] 128x64 tile, BK=32, depth-2 dbuf, single barrier/K-step,
// plain n-major grid. grid (I/64, E*128).
__global__ __launch_bounds__(256, 3) void gemm_gateup(
    const unsigned short* __restrict__ xb, const unsigned short* __restrict__ wgt,
    const unsigned short* __restrict__ wut, const int* __restrict__ list,
    const int* __restrict__ cnt, const float* __restrict__ pwv,
    unsigned short* __restrict__ hbuf) {
  __shared__ unsigned short As[2][128 * 32];
  __shared__ unsigned short Bg[2][64 * 32];
  __shared__ unsigned short Bu[2][64 * 32];
  __shared__ int rows_s[128];
  __shared__ float pws[128];

  const int tid = threadIdx.x;
  const int e = blockIdx.y >> 7;
  const int mt = blockIdx.y & 127;
  const int ce = cnt[e];
  if (mt * 128 >= ce) return;
  const int n0 = blockIdx.x * 64;

  if (tid < 128) {
    int idx = mt * 128 + tid;
    int pid = list[e * T_TOK + (idx < ce ? idx : 0)];
    rows_s[tid] = pid;
    pws[tid] = pwv[pid];
  }
  __syncthreads();

  const int s0 = tid, s1 = 256 + tid;
  const int q0 = (((s0 & 3) ^ ((s0 >> 3) & 3)) * 8);
  const int q1 = (((s1 & 3) ^ ((s1 >> 3) & 3)) * 8);
  const int tok0 = rows_s[s0 >> 2] >> 1, tok1 = rows_s[s1 >> 2] >> 1;

  const unsigned short* wg_base = wgt + ((size_t)e * I_DIM + n0) * H_DIM;
  const unsigned short* wu_base = wut + ((size_t)e * I_DIM + n0) * H_DIM;
  const unsigned short* a_src0 = xb + (size_t)tok0 * H_DIM + q0;
  const unsigned short* a_src1 = xb + (size_t)tok1 * H_DIM + q1;
  const unsigned short* g_src0 = wg_base + (size_t)(s0 >> 2) * H_DIM + q0;
  const unsigned short* u_src0 = wu_base + (size_t)(s0 >> 2) * H_DIM + q0;

#define STAGE_GU(b, k0)                         \
  do {                                          \
    gload16(a_src0 + (k0), &As[b][s0 * 8]);     \
    gload16(a_src1 + (k0), &As[b][s1 * 8]);     \
    gload16(g_src0 + (k0), &Bg[b][s0 * 8]);     \
    gload16(u_src0 + (k0), &Bu[b][s0 * 8]);     \
  } while (0)

  f32x4 zero = {0.f, 0.f, 0.f, 0.f};
  f32x4 accg[4][2], accu[4][2];
#pragma unroll
  for (int m = 0; m < 4; ++m)
#pragma unroll
    for (int n = 0; n < 2; ++n) { accg[m][n] = zero; accu[m][n] = zero; }

  const int lane = tid & 63;
  const int wv = tid >> 6;
  const int wr = (wv >> 1) * 64;
  const int wc = (wv & 1) * 32;
  const int lr = lane & 15;
  const int lks = (((lane >> 4) ^ ((lr >> 1) & 3)) * 8);

  STAGE_GU(0, 0);

  for (int kt = 0; kt < H_DIM / 32; ++kt) {
    const int cur = kt & 1;
    VMCNT0();
    BAR();
    SCHEDFENCE();
    if (kt < H_DIM / 32 - 1) STAGE_GU(cur ^ 1, (kt + 1) * 32);
    const unsigned short* Ab = As[cur];
    const unsigned short* Bgb = Bg[cur];
    const unsigned short* Bub = Bu[cur];
    short8 a[4], bg[2], bu[2];
#pragma unroll
    for (int m = 0; m < 4; ++m)
      a[m] = *(const short8*)&Ab[(wr + m * 16 + lr) * 32 + lks];
#pragma unroll
    for (int n = 0; n < 2; ++n) {
      bg[n] = *(const short8*)&Bgb[(wc + n * 16 + lr) * 32 + lks];
      bu[n] = *(const short8*)&Bub[(wc + n * 16 + lr) * 32 + lks];
    }
    PRIO1();
#pragma unroll
    for (int m = 0; m < 4; ++m)
#pragma unroll
      for (int n = 0; n < 2; ++n) {
        accg[m][n] = __builtin_amdgcn_mfma_f32_16x16x32_bf16(a[m], bg[n], accg[m][n], 0, 0, 0);
        accu[m][n] = __builtin_amdgcn_mfma_f32_16x16x32_bf16(a[m], bu[n], accu[m][n], 0, 0, 0);
      }
    PRIO0();
  }
#undef STAGE_GU

  const int rr = (lane >> 4) * 4;
#pragma unroll
  for (int m = 0; m < 4; ++m) {
#pragma unroll
    for (int j = 0; j < 4; ++j) {
      int tr = wr + m * 16 + rr + j;
      if (mt * 128 + tr < ce) {
        int pid = rows_s[tr];
        float wgt_r = pws[tr];
        size_t rowb = (size_t)pid * I_DIM + n0 + wc;
#pragma unroll
        for (int n = 0; n < 2; ++n) {
          float g = accg[m][n][j];
          float u = accu[m][n][j];
          float hv = wgt_r * (g / (1.f + __expf(-g))) * u;
          hbuf[rowb + n * 16 + lr] = f2bf(hv);
        }
      }
    }
  }
}

// ---------------- GEMM B: pbuf[pid] = h[pid] @ Wd, grouped by expert --------
// [R17 proven] 128x128 tile, BK=32, 3-deep LDS ring, counted vmcnt,
// chunked XCD remap. grid (H/128, E*128)
__global__ __launch_bounds__(256, 3) void gemm_down(
    const unsigned short* __restrict__ hbuf, const unsigned short* __restrict__ wdt,
    const int* __restrict__ list, const int* __restrict__ cnt,
    unsigned short* __restrict__ pbuf) {
  __shared__ unsigned short As[3][128 * 32];
  __shared__ unsigned short Bs[3][128 * 32];
  __shared__ int rows_s[128];

  const int tid = threadIdx.x;
  const int flat = blockIdx.x + 8 * blockIdx.y;
  const int sw = (flat & 7) * (8192 / 8) + (flat >> 3);
  const int ntile = sw & 7;
  const int mb = sw >> 3;
  const int e = mb >> 7;
  const int mt = mb & 127;
  const int ce = cnt[e];
  if (mt * 128 >= ce) return;
  const int n0 = ntile * 128;

  if (tid < 128) {
    int idx = mt * 128 + tid;
    rows_s[tid] = list[e * T_TOK + (idx < ce ? idx : 0)];
  }
  __syncthreads();

  const int s0 = tid, s1 = 256 + tid;
  const int r0s = s0 >> 2, r1s = s1 >> 2;
  const int q0 = (((s0 & 3) ^ ((s0 >> 3) & 3)) * 8);
  const int q1 = (((s1 & 3) ^ ((s1 >> 3) & 3)) * 8);
  const int pid0 = rows_s[r0s], pid1 = rows_s[r1s];

  const unsigned short* wd_base = wdt + ((size_t)e * H_DIM + n0) * I_DIM;
  const unsigned short* a_src0 = hbuf + (size_t)pid0 * I_DIM + q0;
  const unsigned short* a_src1 = hbuf + (size_t)pid1 * I_DIM + q1;
  const unsigned short* b_src0 = wd_base + (size_t)r0s * I_DIM + q0;
  const unsigned short* b_src1 = wd_base + (size_t)r1s * I_DIM + q1;

#define STAGE_DN(b, k0)                         \
  do {                                          \
    gload16(a_src0 + (k0), &As[b][s0 * 8]);     \
    gload16(a_src1 + (k0), &As[b][s1 * 8]);     \
    gload16(b_src0 + (k0), &Bs[b][s0 * 8]);     \
    gload16(b_src1 + (k0), &Bs[b][s1 * 8]);     \
  } while (0)

  f32x4 zero = {0.f, 0.f, 0.f, 0.f};
  f32x4 acc[4][4];
#pragma unroll
  for (int m = 0; m < 4; ++m)
#pragma unroll
    for (int n = 0; n < 4; ++n) acc[m][n] = zero;

  const int lane = tid & 63;
  const int wv = tid >> 6;
  const int wr = (wv >> 1) * 64;
  const int wc = (wv & 1) * 64;
  const int lr = lane & 15;
  const int lks = (((lane >> 4) ^ ((lr >> 1) & 3)) * 8);

  STAGE_DN(0, 0);
  STAGE_DN(1, 32);

  int rb = 0;
  for (int kt = 0; kt < I_DIM / 32; ++kt) {
    if (kt < I_DIM / 32 - 1) VMCNT4(); else VMCNT0();
    BAR();
    SCHEDFENCE();
    if (kt + 2 < I_DIM / 32) {
      int sb = rb + 2; if (sb >= 3) sb -= 3;
      STAGE_DN(sb, (kt + 2) * 32);
    }
    const unsigned short* Ab = As[rb];
    const unsigned short* Bb = Bs[rb];
    short8 a[4], b[4];
#pragma unroll
    for (int m = 0; m < 4; ++m)
      a[m] = *(const short8*)&Ab[(wr + m * 16 + lr) * 32 + lks];
#pragma unroll
    for (int n = 0; n < 4; ++n)
      b[n] = *(const short8*)&Bb[(wc + n * 16 + lr) * 32 + lks];
    PRIO1();
#pragma unroll
    for (int m = 0; m < 4; ++m)
#pragma unroll
      for (int n = 0; n < 4; ++n)
        acc[m][n] = __builtin_amdgcn_mfma_f32_16x16x32_bf16(a[m], b[n], acc[m][n], 0, 0, 0);
    PRIO0();
    rb = (rb + 1 == 3) ? 0 : rb + 1;
  }
#undef STAGE_DN

  const int rr = (lane >> 4) * 4;
#pragma unroll
  for (int m = 0; m < 4; ++m) {
#pragma unroll
    for (int j = 0; j < 4; ++j) {
      int tr = wr + m * 16 + rr + j;
      if (mt * 128 + tr < ce) {
        int pid = rows_s[tr];
        unsigned short* orow = pbuf + (size_t)pid * H_DIM + n0 + wc;
#pragma unroll
        for (int n = 0; n < 4; ++n)
          orow[n * 16 + lr] = f2bf(acc[m][n][j]);
      }
    }
  }
}

// ---- combine: out[t] = pair[2t] + pair[2t+1], in-place bf16->fp32 ----------
__global__ __launch_bounds__(256) void combine_kernel(float* __restrict__ out) {
  const int tid = threadIdx.x, lane = tid & 63, wv = tid >> 6;
  const int t = blockIdx.x * 4 + wv;
  const unsigned short* p = (const unsigned short*)out;
  const unsigned short* r0 = p + (size_t)(2 * t) * H_DIM + lane * 16;
  const unsigned short* r1 = p + (size_t)(2 * t + 1) * H_DIM + lane * 16;
  short8 a0 = *(const short8*)r0;
  short8 a1 = *(const short8*)(r0 + 8);
  short8 b0 = *(const short8*)r1;
  short8 b1 = *(const short8*)(r1 + 8);
  float res[16];
#pragma unroll
  for (int j = 0; j < 8; ++j) {
    res[j] = bf2f((unsigned short)a0[j]) + bf2f((unsigned short)b0[j]);
    res[8 + j] = bf2f((unsigned short)a1[j]) + bf2f((unsigned short)b1[j]);
  }
  float* orow = out + (size_t)t * H_DIM + lane * 16;
#pragma unroll
  for (int j = 0; j < 4; ++j) {
    float4 w = {res[4 * j], res[4 * j + 1], res[4 * j + 2], res[4 * j + 3]};
    ((float4*)orow)[j] = w;
  }
}

// ---------------- launch ----------------
extern "C" void kernel_launch(void* const* d_in, const int* in_sizes, int n_in,
                              void* d_out, int out_size, void* d_ws, size_t ws_size,
                              hipStream_t stream) {
  const float* x = (const float*)d_in[0];
  const float* gw = (const float*)d_in[1];
  const float* wgf = (const float*)d_in[2];
  const float* wuf = (const float*)d_in[3];
  const float* wdf = (const float*)d_in[4];

  const size_t off_xb   = 0;
  const size_t off_wdt  = 33554432;
  const size_t off_h    = 67108864;
  const size_t off_list = 201326592;
  const size_t off_pw   = 201850880;
  const size_t off_cnt  = 201981952;
  const size_t ws_needed = off_cnt + 64;
  if (ws_size < ws_needed) return;

  char* ws = (char*)d_ws;
  unsigned short* xb   = (unsigned short*)(ws + off_xb);
  unsigned short* wdt  = (unsigned short*)(ws + off_wdt);
  unsigned short* hbuf = (unsigned short*)(ws + off_h);
  int*   list = (int*)(ws + off_list);
  float* pwv  = (float*)(ws + off_pw);
  int*   cnt  = (int*)(ws + off_cnt);
  int*   tke  = (int*)(ws + off_h);  // parks in hbuf (unused until gemm_gateup)

  unsigned short* wgt = (unsigned short*)d_out;
  unsigned short* wut = (unsigned short*)d_out + (size_t)E_NUM * H_DIM * I_DIM;
  unsigned short* pbuf = (unsigned short*)d_out;

  hipMemsetAsync(cnt, 0, E_NUM * sizeof(int), stream);

  convert_router_kernel<<<T_TOK / 8, 256, 0, stream>>>(x, gw, xb, tke, pwv);
  build_lists_kernel<<<T_TOK / 256, 256, 0, stream>>>(tke, list, cnt);
  transpose_convert<<<dim3(E_NUM, H_DIM / 128, I_DIM / 64), 256, 0, stream>>>(
      wgf, wgt, H_DIM, I_DIM);
  transpose_convert<<<dim3(E_NUM, H_DIM / 128, I_DIM / 64), 256, 0, stream>>>(
      wuf, wut, H_DIM, I_DIM);
  transpose_convert<<<dim3(E_NUM, I_DIM / 128, H_DIM / 64), 256, 0, stream>>>(
      wdf, wdt, I_DIM, H_DIM);

  gemm_gateup<<<dim3(I_DIM / 64, E_NUM * 128), 256, 0, stream>>>(
      xb, wgt, wut, list, cnt, pwv, hbuf);

  gemm_down<<<dim3(H_DIM / 128, E_NUM * 128), 256, 0, stream>>>(
      hbuf, wdt, list, cnt, pbuf);

  combine_kernel<<<T_TOK / 4, 256, 0, stream>>>((float*)d_out);
}